// Round 10
// baseline (240.242 us; speedup 1.0000x reference)
//
#include <hip/hip_runtime.h>
#include <hip/hip_bf16.h>

typedef __bf16 bf16_t;
typedef bf16_t bf16x8 __attribute__((ext_vector_type(8)));
typedef bf16_t bf16x4 __attribute__((ext_vector_type(4)));
typedef float  f32x4  __attribute__((ext_vector_type(4)));

constexpr int B_ = 8, C_ = 512, HW_ = 4096, LC_ = 512, CTX_ = 768;

// ---------- prep kernels ----------

__global__ void k_transpose_w(const float* __restrict__ in, bf16_t* __restrict__ out,
                              int R, int Cc) {
    __shared__ float t[32][33];
    int r0 = blockIdx.x * 32, c0 = blockIdx.y * 32;
    int tx = threadIdx.x, ty = threadIdx.y;  // 32 x 8
#pragma unroll
    for (int i = 0; i < 4; ++i)
        t[ty + i * 8][tx] = in[(size_t)(r0 + ty + i * 8) * Cc + c0 + tx];
    __syncthreads();
#pragma unroll
    for (int i = 0; i < 4; ++i)
        out[(size_t)(c0 + ty + i * 8) * R + r0 + tx] = (bf16_t)t[tx][ty + i * 8];
}

// bkvo[0..511] = bk ; bkvo[512+c] = bo[c] + sum_m bv[m]*Wo[m][c]
__global__ void k_bias(const float* __restrict__ bk, const float* __restrict__ bv,
                       const float* __restrict__ Wo, const float* __restrict__ bo,
                       float* __restrict__ bkvo) {
    int c = blockIdx.x * 256 + threadIdx.x;
    if (c >= 1024) return;
    if (c < 512) { bkvo[c] = bk[c]; return; }
    int cc = c - 512;
    float s = bo[cc];
    for (int m = 0; m < C_; ++m) s += bv[m] * Wo[(size_t)m * C_ + cc];
    bkvo[c] = s;
}

__global__ void k_f32_to_bf16(const float* __restrict__ in, bf16_t* __restrict__ out, int n) {
    int i = (blockIdx.x * 256 + threadIdx.x) * 4;
    if (i >= n) return;
    f32x4 v = *(const f32x4*)(in + i);
    bf16x4 w;
    w[0] = (bf16_t)v.x; w[1] = (bf16_t)v.y; w[2] = (bf16_t)v.z; w[3] = (bf16_t)v.w;
    *(bf16x4*)(out + i) = w;
}

// x [B][C][HW] f32  ->  xt [B][HW][C] bf16
__global__ void k_transpose_x(const float* __restrict__ x, bf16_t* __restrict__ xt) {
    __shared__ float t[32][33];
    int b = blockIdx.z;
    int p0 = blockIdx.x * 32, c0 = blockIdx.y * 32;
    const float* xb = x + (size_t)b * C_ * HW_;
    bf16_t* xtb = xt + (size_t)b * HW_ * C_;
    int tx = threadIdx.x, ty = threadIdx.y;  // 32 x 8
#pragma unroll
    for (int i = 0; i < 4; ++i) {
        int c = c0 + ty + i * 8;
        t[ty + i * 8][tx] = xb[(size_t)c * HW_ + p0 + tx];
    }
    __syncthreads();
#pragma unroll
    for (int i = 0; i < 4; ++i) {
        int p = p0 + ty + i * 8;
        xtb[(size_t)p * C_ + c0 + tx] = (bf16_t)t[tx][ty + i * 8];
    }
}

// ---------- projection GEMM ----------
// MODE 3: out bf16 transposed [N][Mtot], Mtot passed in sOut: out[n][m] = acc
// MODE 4: merged K|V': N=1024. cc<512 -> Kb[r0*512+cc] = acc + bias[cc]
//         cc>=512 -> Vt (= out_ + B*LC*C elems)[b][cc-512][l] = acc + bias[cc]
template <int MODE>
__global__ __launch_bounds__(256) void k_gemm(
    const bf16_t* __restrict__ A, int lda, long sA,
    const bf16_t* __restrict__ Bt, int ldb, long sB,
    const float* __restrict__ bias,
    void* __restrict__ out_, long sOut,
    int N, int K, float scale) {
    __shared__ bf16_t lA[128 * 32];
    __shared__ bf16_t lB[128 * 32];
    const int z = blockIdx.z;
    A  += (size_t)z * sA;
    Bt += (size_t)z * sB;
    const int tid  = threadIdx.x;
    const int lane = tid & 63;
    const int wave = tid >> 6;
    const int wm = (wave >> 1) * 64, wn = (wave & 1) * 64;
    const int bm0 = blockIdx.y * 128, bn0 = blockIdx.x * 128;
    const int ar = lane & 15, kc = lane >> 4;

    auto lA3 = (__attribute__((address_space(3))) char*)&lA[0];
    auto lB3 = (__attribute__((address_space(3))) char*)&lB[0];

    f32x4 acc[4][4] = {};

    for (int k0 = 0; k0 < K; k0 += 32) {
        __syncthreads();
#pragma unroll
        for (int s = 0; s < 2; ++s) {
            int wchunk = wave * 2 + s;
            int id = wchunk * 64 + lane;
            int row = id >> 2, c4 = id & 3;
            __builtin_amdgcn_global_load_lds(
                (const __attribute__((address_space(1))) void*)
                    &A[(size_t)(bm0 + row) * lda + k0 + c4 * 8],
                (__attribute__((address_space(3))) void*)(lA3 + wchunk * 1024),
                16, 0, 0);
            __builtin_amdgcn_global_load_lds(
                (const __attribute__((address_space(1))) void*)
                    &Bt[(size_t)(bn0 + row) * ldb + k0 + c4 * 8],
                (__attribute__((address_space(3))) void*)(lB3 + wchunk * 1024),
                16, 0, 0);
        }
        __syncthreads();
        bf16x8 af[4], bfr[4];
#pragma unroll
        for (int f = 0; f < 4; ++f) {
            af[f]  = *(const bf16x8*)&lA[(wm + f * 16 + ar) * 32 + kc * 8];
            bfr[f] = *(const bf16x8*)&lB[(wn + f * 16 + ar) * 32 + kc * 8];
        }
#pragma unroll
        for (int fm = 0; fm < 4; ++fm)
#pragma unroll
            for (int fn = 0; fn < 4; ++fn)
                acc[fm][fn] = __builtin_amdgcn_mfma_f32_16x16x32_bf16(
                    af[fm], bfr[fn], acc[fm][fn], 0, 0, 0);
    }

    const int rj = (lane >> 4) * 4;
    const int cj = lane & 15;

#pragma unroll
    for (int fm = 0; fm < 4; ++fm) {
#pragma unroll
        for (int fn = 0; fn < 4; ++fn) {
            int r0 = bm0 + wm + fm * 16 + rj;
            int cc = bn0 + wn + fn * 16 + cj;
            if constexpr (MODE == 3) {
                bf16_t* out = (bf16_t*)out_;
                bf16x4 v;
#pragma unroll
                for (int j = 0; j < 4; ++j) v[j] = (bf16_t)acc[fm][fn][j];
                *(bf16x4*)&out[(size_t)cc * sOut + r0] = v;
            } else {  // MODE 4
                float bb = bias[cc];
                if (cc < 512) {
                    bf16_t* o = (bf16_t*)out_;
#pragma unroll
                    for (int j = 0; j < 4; ++j)
                        o[(size_t)(r0 + j) * 512 + cc] = (bf16_t)(acc[fm][fn][j] + bb);
                } else {
                    bf16_t* o = (bf16_t*)out_ + (size_t)B_ * LC_ * C_;
                    int b = r0 >> 9, l0 = r0 & 511;
                    bf16x4 v;
#pragma unroll
                    for (int j = 0; j < 4; ++j) v[j] = (bf16_t)(acc[fm][fn][j] + bb);
                    *(bf16x4*)&o[((size_t)b * C_ + (cc - 512)) * LC_ + l0] = v;
                }
            }
        }
    }
}

// ---------- fused Q-proj + flash attention, depth-2 counted pipeline ----------
// Block: 64 q-rows. 8 waves = 2(M: 32q) x 4(N: 128 cols). grid=512, z=bid&7.
// A-operands (xt, then Q, then P) live in REGISTERS (afr[2][16]); the LDS is
// 4 x 32KB rotating stream buffers (Wq_t / K / V tiles, [512 rows][32 k]),
// staged via global_load_lds with counted s_waitcnt vmcnt(8) (T4: never drain
// to 0 in-loop). Q/P exchanges go through buffers 0..1 (64KB) at phase
// boundaries under full __syncthreads.
__global__ __launch_bounds__(512, 2) void k_flash(
    const bf16_t* __restrict__ xt, const bf16_t* __restrict__ Wq_t,
    const float* __restrict__ bq,
    const bf16_t* __restrict__ Kb, const bf16_t* __restrict__ Vt,
    const float* __restrict__ x, float* __restrict__ out) {
    __shared__ bf16_t lS[4][16384];     // 4 x 32 KB stream buffers
    __shared__ float redA[4][64];
    __shared__ float redB[4][64];

    const int bid = blockIdx.x;
    const int z = bid & 7;
    const int q0 = (bid >> 3) * 64;
    const int tid = threadIdx.x;
    const int lane = tid & 63;
    const int wave = tid >> 6;
    const int wm2 = wave >> 2;   // 0..1 : 32-q-row group
    const int wn4 = wave & 3;    // 0..3 : 128-col group
    const int h = lane >> 4;     // 0..3
    const int r15 = lane & 15;

    const bf16_t* Az = xt + ((size_t)z * HW_ + q0) * C_;
    const bf16_t* Kz = Kb + (size_t)z * LC_ * C_;
    const bf16_t* Vz = Vt + (size_t)z * C_ * LC_;
    bf16_t* lQP = &lS[0][0];    // 64 KB exchange area (buffers 0..1)

    auto lS3 = (__attribute__((address_space(3))) char*)&lS[0][0];

    // stage one [512 rows][32 k] tile into buffer b; source chunk pre-swizzled
    auto STAGE = [&](int b, const bf16_t* __restrict__ src, int t) {
#pragma unroll
        for (int s = 0; s < 4; ++s) {
            int id = s * 512 + tid;
            int row = id >> 2, c4 = id & 3;
            int c4s = c4 ^ (row & 3);
            __builtin_amdgcn_global_load_lds(
                (const __attribute__((address_space(1))) void*)
                    &src[(size_t)row * 512 + t * 32 + c4s * 8],
                (__attribute__((address_space(3))) void*)
                    (lS3 + b * 32768 + s * 8192 + wave * 1024),
                16, 0, 0);
        }
    };

    bf16x8 afr[2][16];   // A-fragments in registers (xt -> Q -> P)

    // ===== prologue: xt A-frags + first 3 Wq tiles =====
#pragma unroll
    for (int m = 0; m < 2; ++m)
#pragma unroll
        for (int t = 0; t < 16; ++t)
            afr[m][t] = *(const bf16x8*)
                &Az[(size_t)(wm2 * 32 + m * 16 + r15) * C_ + t * 32 + h * 8];
    STAGE(0, Wq_t, 0); STAGE(1, Wq_t, 1); STAGE(2, Wq_t, 2);
    __syncthreads();

    // ===== phase 1: Q = xt @ Wq_t  (buffer offset 0) =====
    f32x4 acc[2][8] = {};
#pragma unroll
    for (int t = 0; t < 16; ++t) {
        if (t + 3 <= 15) STAGE((t + 3) & 3, Wq_t, t + 3);
        bf16x8 bfr[8];
        const bf16_t* lb = &lS[t & 3][0];
#pragma unroll
        for (int n = 0; n < 8; ++n) {
            int row = wn4 * 128 + n * 16 + r15;
            bfr[n] = *(const bf16x8*)&lb[row * 32 + (h ^ (row & 3)) * 8];
        }
#pragma unroll
        for (int m = 0; m < 2; ++m)
#pragma unroll
            for (int n = 0; n < 8; ++n)
                acc[m][n] = __builtin_amdgcn_mfma_f32_16x16x32_bf16(
                    afr[m][t], bfr[n], acc[m][n], 0, 0, 0);
        if (t <= 12)      asm volatile("s_waitcnt vmcnt(8)" ::: "memory");
        else if (t == 13) asm volatile("s_waitcnt vmcnt(4)" ::: "memory");
        else if (t == 14) asm volatile("s_waitcnt vmcnt(0)" ::: "memory");
        __builtin_amdgcn_sched_barrier(0);
        __builtin_amdgcn_s_barrier();
        __builtin_amdgcn_sched_barrier(0);
    }

    // ===== boundary 1: Q exchange (acc -> lQP -> afr) =====
    __syncthreads();
    STAGE(2, Kz, 0); STAGE(3, Kz, 1);   // early K stages into non-lQP buffers
    {
        float bqv[8];
#pragma unroll
        for (int n = 0; n < 8; ++n) bqv[n] = bq[wn4 * 128 + n * 16 + r15];
#pragma unroll
        for (int m = 0; m < 2; ++m)
#pragma unroll
            for (int j = 0; j < 4; ++j) {
                int row = wm2 * 32 + m * 16 + h * 4 + j;
#pragma unroll
                for (int n = 0; n < 8; ++n) {
                    int col = wn4 * 128 + n * 16 + r15;
                    int c16 = col >> 3;
                    int sc = (c16 & 56) | ((c16 ^ row) & 7);
                    lQP[row * 512 + sc * 8 + (col & 7)] = (bf16_t)(acc[m][n][j] + bqv[n]);
                }
            }
    }
    __syncthreads();
#pragma unroll
    for (int m = 0; m < 2; ++m)
#pragma unroll
        for (int t = 0; t < 16; ++t) {
            int row = wm2 * 32 + m * 16 + r15;
            int c16 = t * 4 + h;
            int sc = (c16 & 56) | ((c16 ^ row) & 7);
            afr[m][t] = *(const bf16x8*)&lQP[row * 512 + sc * 8];
        }
    __syncthreads();
    STAGE(0, Kz, 2);
    asm volatile("s_waitcnt vmcnt(8)" ::: "memory");
    __builtin_amdgcn_sched_barrier(0);
    __builtin_amdgcn_s_barrier();
    __builtin_amdgcn_sched_barrier(0);

    // ===== phase 2: S = Q @ K^T  (buffer offset 2: tile j -> buf (j+2)&3) =====
#pragma unroll
    for (int m = 0; m < 2; ++m)
#pragma unroll
        for (int n = 0; n < 8; ++n) acc[m][n] = (f32x4)0.f;
#pragma unroll
    for (int t = 0; t < 16; ++t) {
        if (t + 3 <= 15) STAGE((t + 3 + 2) & 3, Kz, t + 3);
        bf16x8 bfr[8];
        const bf16_t* lb = &lS[(t + 2) & 3][0];
#pragma unroll
        for (int n = 0; n < 8; ++n) {
            int row = wn4 * 128 + n * 16 + r15;
            bfr[n] = *(const bf16x8*)&lb[row * 32 + (h ^ (row & 3)) * 8];
        }
#pragma unroll
        for (int m = 0; m < 2; ++m)
#pragma unroll
            for (int n = 0; n < 8; ++n)
                acc[m][n] = __builtin_amdgcn_mfma_f32_16x16x32_bf16(
                    afr[m][t], bfr[n], acc[m][n], 0, 0, 0);
        if (t <= 12)      asm volatile("s_waitcnt vmcnt(8)" ::: "memory");
        else if (t == 13) asm volatile("s_waitcnt vmcnt(4)" ::: "memory");
        else if (t == 14) asm volatile("s_waitcnt vmcnt(0)" ::: "memory");
        __builtin_amdgcn_sched_barrier(0);
        __builtin_amdgcn_s_barrier();
        __builtin_amdgcn_sched_barrier(0);
    }

    // ===== boundary 2: softmax + P exchange =====
    __syncthreads();
    STAGE(2, Vz, 0); STAGE(3, Vz, 1);   // early V stages
    const float scale = 0.044194173824159216f;  // 512^-0.5
    float M[2][4], inv[2][4];
#pragma unroll
    for (int m = 0; m < 2; ++m)
#pragma unroll
        for (int j = 0; j < 4; ++j) {
            float v = -1e30f;
#pragma unroll
            for (int n = 0; n < 8; ++n) v = fmaxf(v, acc[m][n][j]);
#pragma unroll
            for (int o = 1; o < 16; o <<= 1) v = fmaxf(v, __shfl_xor(v, o));
            if (r15 == 0) redA[wn4][wm2 * 32 + m * 16 + h * 4 + j] = v;
        }
    __syncthreads();
#pragma unroll
    for (int m = 0; m < 2; ++m)
#pragma unroll
        for (int j = 0; j < 4; ++j) {
            int row = wm2 * 32 + m * 16 + h * 4 + j;
            M[m][j] = fmaxf(fmaxf(redA[0][row], redA[1][row]),
                            fmaxf(redA[2][row], redA[3][row]));
        }
#pragma unroll
    for (int m = 0; m < 2; ++m)
#pragma unroll
        for (int j = 0; j < 4; ++j) {
            float s = 0.f;
#pragma unroll
            for (int n = 0; n < 8; ++n) {
                float e = __expf((acc[m][n][j] - M[m][j]) * scale);
                acc[m][n][j] = e;
                s += e;
            }
#pragma unroll
            for (int o = 1; o < 16; o <<= 1) s += __shfl_xor(s, o);
            if (r15 == 0) redB[wn4][wm2 * 32 + m * 16 + h * 4 + j] = s;
        }
    __syncthreads();
#pragma unroll
    for (int m = 0; m < 2; ++m)
#pragma unroll
        for (int j = 0; j < 4; ++j) {
            int row = wm2 * 32 + m * 16 + h * 4 + j;
            inv[m][j] = 1.f / (redB[0][row] + redB[1][row] +
                               redB[2][row] + redB[3][row]);
        }
    // write P into lQP (swizzled)
#pragma unroll
    for (int m = 0; m < 2; ++m)
#pragma unroll
        for (int j = 0; j < 4; ++j) {
            int row = wm2 * 32 + m * 16 + h * 4 + j;
#pragma unroll
            for (int n = 0; n < 8; ++n) {
                int col = wn4 * 128 + n * 16 + r15;
                int c16 = col >> 3;
                int sc = (c16 & 56) | ((c16 ^ row) & 7);
                lQP[row * 512 + sc * 8 + (col & 7)] = (bf16_t)(acc[m][n][j] * inv[m][j]);
            }
        }
    __syncthreads();
#pragma unroll
    for (int m = 0; m < 2; ++m)
#pragma unroll
        for (int t = 0; t < 16; ++t) {
            int row = wm2 * 32 + m * 16 + r15;
            int c16 = t * 4 + h;
            int sc = (c16 & 56) | ((c16 ^ row) & 7);
            afr[m][t] = *(const bf16x8*)&lQP[row * 512 + sc * 8];
        }
    __syncthreads();
    STAGE(0, Vz, 2);
    asm volatile("s_waitcnt vmcnt(8)" ::: "memory");
    __builtin_amdgcn_sched_barrier(0);
    __builtin_amdgcn_s_barrier();
    __builtin_amdgcn_sched_barrier(0);

    // ===== phase 3: O = P @ V  (buffer offset 2) =====
    f32x4 oac[2][8] = {};
#pragma unroll
    for (int t = 0; t < 16; ++t) {
        if (t + 3 <= 15) STAGE((t + 3 + 2) & 3, Vz, t + 3);
        bf16x8 bfr[8];
        const bf16_t* lb = &lS[(t + 2) & 3][0];
#pragma unroll
        for (int n = 0; n < 8; ++n) {
            int row = wn4 * 128 + n * 16 + r15;
            bfr[n] = *(const bf16x8*)&lb[row * 32 + (h ^ (row & 3)) * 8];
        }
#pragma unroll
        for (int m = 0; m < 2; ++m)
#pragma unroll
            for (int n = 0; n < 8; ++n)
                oac[m][n] = __builtin_amdgcn_mfma_f32_16x16x32_bf16(
                    afr[m][t], bfr[n], oac[m][n], 0, 0, 0);
        if (t <= 12)      asm volatile("s_waitcnt vmcnt(8)" ::: "memory");
        else if (t == 13) asm volatile("s_waitcnt vmcnt(4)" ::: "memory");
        else if (t == 14) asm volatile("s_waitcnt vmcnt(0)" ::: "memory");
        __builtin_amdgcn_sched_barrier(0);
        __builtin_amdgcn_s_barrier();
        __builtin_amdgcn_sched_barrier(0);
    }

    // ===== epilogue: out[c][hw] = O + x[c][hw] =====
    float* oz = out + (size_t)z * C_ * HW_;
    const float* xz = x + (size_t)z * C_ * HW_;
#pragma unroll
    for (int m = 0; m < 2; ++m)
#pragma unroll
        for (int n = 0; n < 8; ++n) {
            int r0 = q0 + wm2 * 32 + m * 16 + h * 4;
            int cc = wn4 * 128 + n * 16 + r15;
            f32x4 xv = *(const f32x4*)&xz[(size_t)cc * HW_ + r0];
            f32x4 o;
#pragma unroll
            for (int j = 0; j < 4; ++j) o[j] = oac[m][n][j] + xv[j];
            *(f32x4*)&oz[(size_t)cc * HW_ + r0] = o;
        }
}

extern "C" void kernel_launch(void* const* d_in, const int* in_sizes, int n_in,
                              void* d_out, int out_size, void* d_ws, size_t ws_size,
                              hipStream_t stream) {
    (void)in_sizes; (void)n_in; (void)out_size; (void)ws_size;
    const float* x   = (const float*)d_in[0];
    const float* ctx = (const float*)d_in[1];
    const float* Wq  = (const float*)d_in[2];
    const float* bq  = (const float*)d_in[3];
    const float* Wk  = (const float*)d_in[4];
    const float* bk  = (const float*)d_in[5];
    const float* Wv  = (const float*)d_in[6];
    const float* bv  = (const float*)d_in[7];
    const float* Wo  = (const float*)d_in[8];
    const float* bo  = (const float*)d_in[9];
    float* out = (float*)d_out;

    char* ws = (char*)d_ws;
    size_t off = 0;
    auto alloc = [&](size_t bytes) {
        char* p = ws + off;
        off += (bytes + 255) & ~(size_t)255;
        return p;
    };
    bf16_t* Wq_t  = (bf16_t*)alloc((size_t)C_ * C_ * 2);
    bf16_t* Wk_t  = (bf16_t*)alloc((size_t)C_ * CTX_ * 2);   // adjacent ...
    bf16_t* Wvo_t = (bf16_t*)alloc((size_t)C_ * CTX_ * 2);   // ... to Wk_t (N=1024 concat)
    bf16_t* Wv_b  = (bf16_t*)alloc((size_t)CTX_ * C_ * 2);
    bf16_t* Wo_t  = (bf16_t*)alloc((size_t)C_ * C_ * 2);
    float*  bkvo  = (float*)alloc((size_t)1024 * 4);
    bf16_t* ctxb  = (bf16_t*)alloc((size_t)B_ * LC_ * CTX_ * 2);
    bf16_t* xt    = (bf16_t*)alloc((size_t)B_ * HW_ * C_ * 2);
    bf16_t* Kb    = (bf16_t*)alloc((size_t)B_ * LC_ * C_ * 2);  // adjacent ...
    bf16_t* Vt    = (bf16_t*)alloc((size_t)B_ * C_ * LC_ * 2);  // ... to Kb (MODE 4)

    // weight prep
    k_transpose_w<<<dim3(C_ / 32, C_ / 32), dim3(32, 8), 0, stream>>>(Wq, Wq_t, C_, C_);
    k_transpose_w<<<dim3(CTX_ / 32, C_ / 32), dim3(32, 8), 0, stream>>>(Wk, Wk_t, CTX_, C_);
    k_transpose_w<<<dim3(C_ / 32, C_ / 32), dim3(32, 8), 0, stream>>>(Wo, Wo_t, C_, C_);
    k_f32_to_bf16<<<(CTX_ * C_ / 4 + 255) / 256, 256, 0, stream>>>(Wv, Wv_b, CTX_ * C_);
    k_bias<<<4, 256, 0, stream>>>(bk, bv, Wo, bo, bkvo);
    k_f32_to_bf16<<<(B_ * LC_ * CTX_ / 4 + 255) / 256, 256, 0, stream>>>(
        ctx, ctxb, B_ * LC_ * CTX_);
    k_transpose_x<<<dim3(HW_ / 32, C_ / 32, B_), dim3(32, 8), 0, stream>>>(x, xt);

    // Wvo_t = (Wv @ Wo)^T
    k_gemm<3><<<dim3(4, 6, 1), 256, 0, stream>>>(
        Wv_b, C_, 0, Wo_t, C_, 0, nullptr, Wvo_t, CTX_, C_, C_, 1.f);
    // merged: [K | V'] = ctx @ [Wk | Wvo] + bkvo  (one 256-block launch)
    k_gemm<4><<<dim3(8, 32, 1), 256, 0, stream>>>(
        ctxb, CTX_, 0, Wk_t, CTX_, 0, bkvo, Kb, 0, 1024, CTX_, 1.f);
    // fused Q-projection + attention + residual
    k_flash<<<512, 512, 0, stream>>>(xt, Wq_t, bq, Kb, Vt, x, out);
}

// Round 11
// 196.498 us; speedup vs baseline: 1.2226x; 1.2226x over previous
//
#include <hip/hip_runtime.h>
#include <hip/hip_bf16.h>

typedef __bf16 bf16_t;
typedef bf16_t bf16x8 __attribute__((ext_vector_type(8)));
typedef bf16_t bf16x4 __attribute__((ext_vector_type(4)));
typedef float  f32x4  __attribute__((ext_vector_type(4)));

constexpr int B_ = 8, C_ = 512, HW_ = 4096, LC_ = 512, CTX_ = 768;

// ---------- prep kernels ----------

__global__ void k_transpose_w(const float* __restrict__ in, bf16_t* __restrict__ out,
                              int R, int Cc) {
    __shared__ float t[32][33];
    int r0 = blockIdx.x * 32, c0 = blockIdx.y * 32;
    int tx = threadIdx.x, ty = threadIdx.y;  // 32 x 8
#pragma unroll
    for (int i = 0; i < 4; ++i)
        t[ty + i * 8][tx] = in[(size_t)(r0 + ty + i * 8) * Cc + c0 + tx];
    __syncthreads();
#pragma unroll
    for (int i = 0; i < 4; ++i)
        out[(size_t)(c0 + ty + i * 8) * R + r0 + tx] = (bf16_t)t[tx][ty + i * 8];
}

// bkvo[0..511] = bk ; bkvo[512+c] = bo[c] + sum_m bv[m]*Wo[m][c]
__global__ void k_bias(const float* __restrict__ bk, const float* __restrict__ bv,
                       const float* __restrict__ Wo, const float* __restrict__ bo,
                       float* __restrict__ bkvo) {
    int c = blockIdx.x * 256 + threadIdx.x;
    if (c >= 1024) return;
    if (c < 512) { bkvo[c] = bk[c]; return; }
    int cc = c - 512;
    float s = bo[cc];
    for (int m = 0; m < C_; ++m) s += bv[m] * Wo[(size_t)m * C_ + cc];
    bkvo[c] = s;
}

__global__ void k_f32_to_bf16(const float* __restrict__ in, bf16_t* __restrict__ out, int n) {
    int i = (blockIdx.x * 256 + threadIdx.x) * 4;
    if (i >= n) return;
    f32x4 v = *(const f32x4*)(in + i);
    bf16x4 w;
    w[0] = (bf16_t)v.x; w[1] = (bf16_t)v.y; w[2] = (bf16_t)v.z; w[3] = (bf16_t)v.w;
    *(bf16x4*)(out + i) = w;
}

// x [B][C][HW] f32  ->  xt [B][HW][C] bf16
__global__ void k_transpose_x(const float* __restrict__ x, bf16_t* __restrict__ xt) {
    __shared__ float t[32][33];
    int b = blockIdx.z;
    int p0 = blockIdx.x * 32, c0 = blockIdx.y * 32;
    const float* xb = x + (size_t)b * C_ * HW_;
    bf16_t* xtb = xt + (size_t)b * HW_ * C_;
    int tx = threadIdx.x, ty = threadIdx.y;  // 32 x 8
#pragma unroll
    for (int i = 0; i < 4; ++i) {
        int c = c0 + ty + i * 8;
        t[ty + i * 8][tx] = xb[(size_t)c * HW_ + p0 + tx];
    }
    __syncthreads();
#pragma unroll
    for (int i = 0; i < 4; ++i) {
        int p = p0 + ty + i * 8;
        xtb[(size_t)p * C_ + c0 + tx] = (bf16_t)t[tx][ty + i * 8];
    }
}

// ---------- projection GEMM ----------
// MODE 3: out bf16 transposed [N][Mtot], Mtot passed in sOut: out[n][m] = acc
// MODE 4: merged K|V': N=1024. cc<512 -> Kb[r0*512+cc] = acc + bias[cc]
//         cc>=512 -> Vt (= out_ + B*LC*C elems)[b][cc-512][l] = acc + bias[cc]
template <int MODE>
__global__ __launch_bounds__(256) void k_gemm(
    const bf16_t* __restrict__ A, int lda, long sA,
    const bf16_t* __restrict__ Bt, int ldb, long sB,
    const float* __restrict__ bias,
    void* __restrict__ out_, long sOut,
    int N, int K, float scale) {
    __shared__ bf16_t lA[128 * 32];
    __shared__ bf16_t lB[128 * 32];
    const int z = blockIdx.z;
    A  += (size_t)z * sA;
    Bt += (size_t)z * sB;
    const int tid  = threadIdx.x;
    const int lane = tid & 63;
    const int wave = tid >> 6;
    const int wm = (wave >> 1) * 64, wn = (wave & 1) * 64;
    const int bm0 = blockIdx.y * 128, bn0 = blockIdx.x * 128;
    const int ar = lane & 15, kc = lane >> 4;

    auto lA3 = (__attribute__((address_space(3))) char*)&lA[0];
    auto lB3 = (__attribute__((address_space(3))) char*)&lB[0];

    f32x4 acc[4][4] = {};

    for (int k0 = 0; k0 < K; k0 += 32) {
        __syncthreads();
#pragma unroll
        for (int s = 0; s < 2; ++s) {
            int wchunk = wave * 2 + s;
            int id = wchunk * 64 + lane;
            int row = id >> 2, c4 = id & 3;
            __builtin_amdgcn_global_load_lds(
                (const __attribute__((address_space(1))) void*)
                    &A[(size_t)(bm0 + row) * lda + k0 + c4 * 8],
                (__attribute__((address_space(3))) void*)(lA3 + wchunk * 1024),
                16, 0, 0);
            __builtin_amdgcn_global_load_lds(
                (const __attribute__((address_space(1))) void*)
                    &Bt[(size_t)(bn0 + row) * ldb + k0 + c4 * 8],
                (__attribute__((address_space(3))) void*)(lB3 + wchunk * 1024),
                16, 0, 0);
        }
        __syncthreads();
        bf16x8 af[4], bfr[4];
#pragma unroll
        for (int f = 0; f < 4; ++f) {
            af[f]  = *(const bf16x8*)&lA[(wm + f * 16 + ar) * 32 + kc * 8];
            bfr[f] = *(const bf16x8*)&lB[(wn + f * 16 + ar) * 32 + kc * 8];
        }
#pragma unroll
        for (int fm = 0; fm < 4; ++fm)
#pragma unroll
            for (int fn = 0; fn < 4; ++fn)
                acc[fm][fn] = __builtin_amdgcn_mfma_f32_16x16x32_bf16(
                    af[fm], bfr[fn], acc[fm][fn], 0, 0, 0);
    }

    const int rj = (lane >> 4) * 4;
    const int cj = lane & 15;

#pragma unroll
    for (int fm = 0; fm < 4; ++fm) {
#pragma unroll
        for (int fn = 0; fn < 4; ++fn) {
            int r0 = bm0 + wm + fm * 16 + rj;
            int cc = bn0 + wn + fn * 16 + cj;
            if constexpr (MODE == 3) {
                bf16_t* out = (bf16_t*)out_;
                bf16x4 v;
#pragma unroll
                for (int j = 0; j < 4; ++j) v[j] = (bf16_t)acc[fm][fn][j];
                *(bf16x4*)&out[(size_t)cc * sOut + r0] = v;
            } else {  // MODE 4
                float bb = bias[cc];
                if (cc < 512) {
                    bf16_t* o = (bf16_t*)out_;
#pragma unroll
                    for (int j = 0; j < 4; ++j)
                        o[(size_t)(r0 + j) * 512 + cc] = (bf16_t)(acc[fm][fn][j] + bb);
                } else {
                    bf16_t* o = (bf16_t*)out_ + (size_t)B_ * LC_ * C_;
                    int b = r0 >> 9, l0 = r0 & 511;
                    bf16x4 v;
#pragma unroll
                    for (int j = 0; j < 4; ++j) v[j] = (bf16_t)(acc[fm][fn][j] + bb);
                    *(bf16x4*)&o[((size_t)b * C_ + (cc - 512)) * LC_ + l0] = v;
                }
            }
        }
    }
}

// ---------- fused Q-proj + flash attention, 3-buffer counted-vmcnt pipeline ----------
// Block: 64 q-rows, 8 waves = 2(M:32q) x 4(N:128cols). grid=512, z=bid&7 XCD pin.
// lQP (64KB, swizzled) holds the A-operand: xt -> Q -> P; read per step (2x b128).
// lS = 3 x 32KB rotating stream buffers ([512 rows][32 k]) staged 2 tiles ahead
// via global_load_lds; in-loop wait is s_waitcnt vmcnt(4) (T4: never 0 mid-loop).
// Softmax reduce arrays alias dead lQP rows (Q dead at that point).
__global__ __launch_bounds__(512, 2) void k_flash(
    const bf16_t* __restrict__ xt, const bf16_t* __restrict__ Wq_t,
    const float* __restrict__ bq,
    const bf16_t* __restrict__ Kb, const bf16_t* __restrict__ Vt,
    const float* __restrict__ x, float* __restrict__ out) {
    __shared__ bf16_t lQP[64 * 512];    // 64 KB
    __shared__ bf16_t lS[3][16384];     // 96 KB  (total 160 KiB exactly)
    float (*redA)[64] = (float(*)[64])&lQP[0];      // alias: rows 0-1 of lQP
    float (*redB)[64] = (float(*)[64])&lQP[512];    // alias: rows 2-3 of lQP

    const int bid = blockIdx.x;
    const int z = bid & 7;
    const int q0 = (bid >> 3) * 64;
    const int tid = threadIdx.x;
    const int lane = tid & 63;
    const int wave = tid >> 6;
    const int wm2 = wave >> 2;   // 0..1 : 32-q-row group
    const int wn4 = wave & 3;    // 0..3 : 128-col group
    const int h = lane >> 4;     // 0..3
    const int r15 = lane & 15;

    const bf16_t* Az = xt + ((size_t)z * HW_ + q0) * C_;
    const bf16_t* Kz = Kb + (size_t)z * LC_ * C_;
    const bf16_t* Vz = Vt + (size_t)z * C_ * LC_;

    auto lQ3 = (__attribute__((address_space(3))) char*)&lQP[0];
    auto lS3 = (__attribute__((address_space(3))) char*)&lS[0][0];

    // stage one [512 rows][32 k] tile (32 KB) into buffer b; source pre-swizzled
    auto STAGE = [&](int b, const bf16_t* __restrict__ src, int t) {
#pragma unroll
        for (int s = 0; s < 4; ++s) {
            int id = s * 512 + tid;
            int row = id >> 2, c4 = id & 3;
            int c4s = c4 ^ (row & 3);
            __builtin_amdgcn_global_load_lds(
                (const __attribute__((address_space(1))) void*)
                    &src[(size_t)row * 512 + t * 32 + c4s * 8],
                (__attribute__((address_space(3))) void*)
                    (lS3 + b * 32768 + s * 8192 + wave * 1024),
                16, 0, 0);
        }
    };

    f32x4 acc[2][8];

    // A-frags from lQP + B-frags from lS[buf] -> 16 MFMA
    auto STEP = [&](int t, int buf) {
        bf16x8 af[2], bfr[8];
        int c16 = t * 4 + h;
#pragma unroll
        for (int m = 0; m < 2; ++m) {
            int row = wm2 * 32 + m * 16 + r15;
            int sc = (c16 & 56) | ((c16 ^ row) & 7);
            af[m] = *(const bf16x8*)&lQP[row * 512 + sc * 8];
        }
        const bf16_t* lb = &lS[buf][0];
#pragma unroll
        for (int n = 0; n < 8; ++n) {
            int row = wn4 * 128 + n * 16 + r15;
            bfr[n] = *(const bf16x8*)&lb[row * 32 + (h ^ (row & 3)) * 8];
        }
        __builtin_amdgcn_s_setprio(1);
#pragma unroll
        for (int m = 0; m < 2; ++m)
#pragma unroll
            for (int n = 0; n < 8; ++n)
                acc[m][n] = __builtin_amdgcn_mfma_f32_16x16x32_bf16(
                    af[m], bfr[n], acc[m][n], 0, 0, 0);
        __builtin_amdgcn_s_setprio(0);
    };

    // one 16-step GEMM phase; tile j lives in buffer (j+off)%3.
    // entry: tiles 0,1 staged & landed; in-loop vmcnt(4) keeps 1 tile in flight.
    auto PHASE = [&](const bf16_t* __restrict__ src, int off) {
        for (int t = 0; t <= 13; ++t) {
            STAGE((t + 2 + off) % 3, src, t + 2);
            STEP(t, (t + off) % 3);
            asm volatile("s_waitcnt vmcnt(4)" ::: "memory");
            __builtin_amdgcn_sched_barrier(0);
            __builtin_amdgcn_s_barrier();
            __builtin_amdgcn_sched_barrier(0);
        }
        STEP(14, (14 + off) % 3);
        asm volatile("s_waitcnt vmcnt(0)" ::: "memory");
        __builtin_amdgcn_sched_barrier(0);
        __builtin_amdgcn_s_barrier();
        __builtin_amdgcn_sched_barrier(0);
        STEP(15, (15 + off) % 3);
    };

    // ===== prologue: xt tile -> lQP (swizzled src), Wq tiles 0,1 -> bufs 0,1 =====
#pragma unroll
    for (int t = 0; t < 8; ++t) {
        int row = wave * 8 + t;
        int c16 = (lane & 56) | ((lane ^ row) & 7);
        __builtin_amdgcn_global_load_lds(
            (const __attribute__((address_space(1))) void*)&Az[(size_t)row * C_ + c16 * 8],
            (__attribute__((address_space(3))) void*)(lQ3 + row * 1024),
            16, 0, 0);
    }
    STAGE(0, Wq_t, 0); STAGE(1, Wq_t, 1);
    __syncthreads();

    // ===== phase 1: Q = xt @ Wq_t =====
#pragma unroll
    for (int m = 0; m < 2; ++m)
#pragma unroll
        for (int n = 0; n < 8; ++n) acc[m][n] = (f32x4)0.f;
    PHASE(Wq_t, 0);

    // ===== boundary 1: Q (+bq) -> lQP; early K stages =====
    __syncthreads();
    STAGE(1, Kz, 0); STAGE(2, Kz, 1);   // phase-2 mapping: tile j -> buf (j+1)%3
    {
        float bqv[8];
#pragma unroll
        for (int n = 0; n < 8; ++n) bqv[n] = bq[wn4 * 128 + n * 16 + r15];
#pragma unroll
        for (int m = 0; m < 2; ++m)
#pragma unroll
            for (int j = 0; j < 4; ++j) {
                int row = wm2 * 32 + m * 16 + h * 4 + j;
#pragma unroll
                for (int n = 0; n < 8; ++n) {
                    int col = wn4 * 128 + n * 16 + r15;
                    int c16 = col >> 3;
                    int sc = (c16 & 56) | ((c16 ^ row) & 7);
                    lQP[row * 512 + sc * 8 + (col & 7)] = (bf16_t)(acc[m][n][j] + bqv[n]);
                }
            }
    }
    __syncthreads();   // drains K0,K1 too

    // ===== phase 2: S = Q @ K^T =====
#pragma unroll
    for (int m = 0; m < 2; ++m)
#pragma unroll
        for (int n = 0; n < 8; ++n) acc[m][n] = (f32x4)0.f;
    PHASE(Kz, 1);

    // ===== boundary 2: softmax, P -> lQP; early V stages =====
    __syncthreads();
    STAGE(2, Vz, 0); STAGE(0, Vz, 1);   // phase-3 mapping: tile j -> buf (j+2)%3
    const float scale = 0.044194173824159216f;  // 512^-0.5
    float M[2][4], inv[2][4];
#pragma unroll
    for (int m = 0; m < 2; ++m)
#pragma unroll
        for (int j = 0; j < 4; ++j) {
            float v = -1e30f;
#pragma unroll
            for (int n = 0; n < 8; ++n) v = fmaxf(v, acc[m][n][j]);
#pragma unroll
            for (int o = 1; o < 16; o <<= 1) v = fmaxf(v, __shfl_xor(v, o));
            if (r15 == 0) redA[wn4][wm2 * 32 + m * 16 + h * 4 + j] = v;
        }
    __syncthreads();
#pragma unroll
    for (int m = 0; m < 2; ++m)
#pragma unroll
        for (int j = 0; j < 4; ++j) {
            int row = wm2 * 32 + m * 16 + h * 4 + j;
            M[m][j] = fmaxf(fmaxf(redA[0][row], redA[1][row]),
                            fmaxf(redA[2][row], redA[3][row]));
        }
#pragma unroll
    for (int m = 0; m < 2; ++m)
#pragma unroll
        for (int j = 0; j < 4; ++j) {
            float s = 0.f;
#pragma unroll
            for (int n = 0; n < 8; ++n) {
                float e = __expf((acc[m][n][j] - M[m][j]) * scale);
                acc[m][n][j] = e;
                s += e;
            }
#pragma unroll
            for (int o = 1; o < 16; o <<= 1) s += __shfl_xor(s, o);
            if (r15 == 0) redB[wn4][wm2 * 32 + m * 16 + h * 4 + j] = s;
        }
    __syncthreads();
#pragma unroll
    for (int m = 0; m < 2; ++m)
#pragma unroll
        for (int j = 0; j < 4; ++j) {
            int row = wm2 * 32 + m * 16 + h * 4 + j;
            inv[m][j] = 1.f / (redB[0][row] + redB[1][row] +
                               redB[2][row] + redB[3][row]);
        }
    __syncthreads();   // red reads done before P overwrites lQP
    // write P (bf16, swizzled) into lQP
#pragma unroll
    for (int m = 0; m < 2; ++m)
#pragma unroll
        for (int j = 0; j < 4; ++j) {
            int row = wm2 * 32 + m * 16 + h * 4 + j;
#pragma unroll
            for (int n = 0; n < 8; ++n) {
                int col = wn4 * 128 + n * 16 + r15;
                int c16 = col >> 3;
                int sc = (c16 & 56) | ((c16 ^ row) & 7);
                lQP[row * 512 + sc * 8 + (col & 7)] = (bf16_t)(acc[m][n][j] * inv[m][j]);
            }
        }
    __syncthreads();   // drains V0,V1 too

    // ===== phase 3: O = P @ V =====
#pragma unroll
    for (int m = 0; m < 2; ++m)
#pragma unroll
        for (int n = 0; n < 8; ++n) acc[m][n] = (f32x4)0.f;
    PHASE(Vz, 2);

    // ===== epilogue: out[c][hw] = O + x[c][hw] =====
    float* oz = out + (size_t)z * C_ * HW_;
    const float* xz = x + (size_t)z * C_ * HW_;
#pragma unroll
    for (int m = 0; m < 2; ++m)
#pragma unroll
        for (int n = 0; n < 8; ++n) {
            int r0 = q0 + wm2 * 32 + m * 16 + h * 4;
            int cc = wn4 * 128 + n * 16 + r15;
            f32x4 xv = *(const f32x4*)&xz[(size_t)cc * HW_ + r0];
            f32x4 o;
#pragma unroll
            for (int j = 0; j < 4; ++j) o[j] = acc[m][n][j] + xv[j];
            *(f32x4*)&oz[(size_t)cc * HW_ + r0] = o;
        }
}

extern "C" void kernel_launch(void* const* d_in, const int* in_sizes, int n_in,
                              void* d_out, int out_size, void* d_ws, size_t ws_size,
                              hipStream_t stream) {
    (void)in_sizes; (void)n_in; (void)out_size; (void)ws_size;
    const float* x   = (const float*)d_in[0];
    const float* ctx = (const float*)d_in[1];
    const float* Wq  = (const float*)d_in[2];
    const float* bq  = (const float*)d_in[3];
    const float* Wk  = (const float*)d_in[4];
    const float* bk  = (const float*)d_in[5];
    const float* Wv  = (const float*)d_in[6];
    const float* bv  = (const float*)d_in[7];
    const float* Wo  = (const float*)d_in[8];
    const float* bo  = (const float*)d_in[9];
    float* out = (float*)d_out;

    char* ws = (char*)d_ws;
    size_t off = 0;
    auto alloc = [&](size_t bytes) {
        char* p = ws + off;
        off += (bytes + 255) & ~(size_t)255;
        return p;
    };
    bf16_t* Wq_t  = (bf16_t*)alloc((size_t)C_ * C_ * 2);
    bf16_t* Wk_t  = (bf16_t*)alloc((size_t)C_ * CTX_ * 2);   // adjacent ...
    bf16_t* Wvo_t = (bf16_t*)alloc((size_t)C_ * CTX_ * 2);   // ... to Wk_t (N=1024 concat)
    bf16_t* Wv_b  = (bf16_t*)alloc((size_t)CTX_ * C_ * 2);
    bf16_t* Wo_t  = (bf16_t*)alloc((size_t)C_ * C_ * 2);
    float*  bkvo  = (float*)alloc((size_t)1024 * 4);
    bf16_t* ctxb  = (bf16_t*)alloc((size_t)B_ * LC_ * CTX_ * 2);
    bf16_t* xt    = (bf16_t*)alloc((size_t)B_ * HW_ * C_ * 2);
    bf16_t* Kb    = (bf16_t*)alloc((size_t)B_ * LC_ * C_ * 2);  // adjacent ...
    bf16_t* Vt    = (bf16_t*)alloc((size_t)B_ * C_ * LC_ * 2);  // ... to Kb (MODE 4)

    // weight prep
    k_transpose_w<<<dim3(C_ / 32, C_ / 32), dim3(32, 8), 0, stream>>>(Wq, Wq_t, C_, C_);
    k_transpose_w<<<dim3(CTX_ / 32, C_ / 32), dim3(32, 8), 0, stream>>>(Wk, Wk_t, CTX_, C_);
    k_transpose_w<<<dim3(C_ / 32, C_ / 32), dim3(32, 8), 0, stream>>>(Wo, Wo_t, C_, C_);
    k_f32_to_bf16<<<(CTX_ * C_ / 4 + 255) / 256, 256, 0, stream>>>(Wv, Wv_b, CTX_ * C_);
    k_bias<<<4, 256, 0, stream>>>(bk, bv, Wo, bo, bkvo);
    k_f32_to_bf16<<<(B_ * LC_ * CTX_ / 4 + 255) / 256, 256, 0, stream>>>(
        ctx, ctxb, B_ * LC_ * CTX_);
    k_transpose_x<<<dim3(HW_ / 32, C_ / 32, B_), dim3(32, 8), 0, stream>>>(x, xt);

    // Wvo_t = (Wv @ Wo)^T
    k_gemm<3><<<dim3(4, 6, 1), 256, 0, stream>>>(
        Wv_b, C_, 0, Wo_t, C_, 0, nullptr, Wvo_t, CTX_, C_, C_, 1.f);
    // merged: [K | V'] = ctx @ [Wk | Wvo] + bkvo  (one 256-block launch)
    k_gemm<4><<<dim3(8, 32, 1), 256, 0, stream>>>(
        ctxb, CTX_, 0, Wk_t, CTX_, 0, bkvo, Kb, 0, 1024, CTX_, 1.f);
    // fused Q-projection + attention + residual
    k_flash<<<512, 512, 0, stream>>>(xt, Wq_t, bq, Kb, Vt, x, out);
}

// Round 12
// 165.627 us; speedup vs baseline: 1.4505x; 1.1864x over previous
//
#include <hip/hip_runtime.h>
#include <hip/hip_bf16.h>

typedef __bf16 bf16_t;
typedef bf16_t bf16x8 __attribute__((ext_vector_type(8)));
typedef bf16_t bf16x4 __attribute__((ext_vector_type(4)));
typedef float  f32x4  __attribute__((ext_vector_type(4)));

constexpr int B_ = 8, C_ = 512, HW_ = 4096, LC_ = 512, CTX_ = 768;

// ---------- prep kernels ----------

__global__ void k_transpose_w(const float* __restrict__ in, bf16_t* __restrict__ out,
                              int R, int Cc) {
    __shared__ float t[32][33];
    int r0 = blockIdx.x * 32, c0 = blockIdx.y * 32;
    int tx = threadIdx.x, ty = threadIdx.y;  // 32 x 8
#pragma unroll
    for (int i = 0; i < 4; ++i)
        t[ty + i * 8][tx] = in[(size_t)(r0 + ty + i * 8) * Cc + c0 + tx];
    __syncthreads();
#pragma unroll
    for (int i = 0; i < 4; ++i)
        out[(size_t)(c0 + ty + i * 8) * R + r0 + tx] = (bf16_t)t[tx][ty + i * 8];
}

// blocks 0..127: wave w -> cc = blk*4+w : bkvo[512+cc] = bo[cc] + sum_m bv[m]*Wo_t[cc][m]
// blocks 128..129: copy bk -> bkvo[0..511]
__global__ void k_bias(const float* __restrict__ bk, const float* __restrict__ bv,
                       const bf16_t* __restrict__ Wo_t, const float* __restrict__ bo,
                       float* __restrict__ bkvo) {
    int blk = blockIdx.x, tid = threadIdx.x;
    if (blk >= 128) {
        int i = (blk - 128) * 256 + tid;
        bkvo[i] = bk[i];
        return;
    }
    int wave = tid >> 6, lane = tid & 63;
    int cc = blk * 4 + wave;
    bf16x8 w = *(const bf16x8*)&Wo_t[(size_t)cc * C_ + lane * 8];
    float s = 0.f;
#pragma unroll
    for (int j = 0; j < 8; ++j) s += bv[lane * 8 + j] * (float)w[j];
#pragma unroll
    for (int o = 32; o > 0; o >>= 1) s += __shfl_xor(s, o);
    if (lane == 0) bkvo[512 + cc] = s + bo[cc];
}

__global__ void k_f32_to_bf16(const float* __restrict__ in, bf16_t* __restrict__ out, int n) {
    int i = (blockIdx.x * 256 + threadIdx.x) * 4;
    if (i >= n) return;
    f32x4 v = *(const f32x4*)(in + i);
    bf16x4 w;
    w[0] = (bf16_t)v.x; w[1] = (bf16_t)v.y; w[2] = (bf16_t)v.z; w[3] = (bf16_t)v.w;
    *(bf16x4*)(out + i) = w;
}

// ---------- projection GEMM ----------
// MODE 3: out bf16 transposed [N][Mtot], Mtot passed in sOut: out[n][m] = acc
// MODE 4: merged K|V': N=1024. cc<512 -> Kb[r0*512+cc] = acc + bias[cc]
//         cc>=512 -> Vt (= out_ + B*LC*C elems)[b][cc-512][l] = acc + bias[cc]
template <int MODE>
__global__ __launch_bounds__(256) void k_gemm(
    const bf16_t* __restrict__ A, int lda, long sA,
    const bf16_t* __restrict__ Bt, int ldb, long sB,
    const float* __restrict__ bias,
    void* __restrict__ out_, long sOut,
    int N, int K, float scale) {
    __shared__ bf16_t lA[128 * 32];
    __shared__ bf16_t lB[128 * 32];
    const int z = blockIdx.z;
    A  += (size_t)z * sA;
    Bt += (size_t)z * sB;
    const int tid  = threadIdx.x;
    const int lane = tid & 63;
    const int wave = tid >> 6;
    const int wm = (wave >> 1) * 64, wn = (wave & 1) * 64;
    const int bm0 = blockIdx.y * 128, bn0 = blockIdx.x * 128;
    const int ar = lane & 15, kc = lane >> 4;

    auto lA3 = (__attribute__((address_space(3))) char*)&lA[0];
    auto lB3 = (__attribute__((address_space(3))) char*)&lB[0];

    f32x4 acc[4][4] = {};

    for (int k0 = 0; k0 < K; k0 += 32) {
        __syncthreads();
#pragma unroll
        for (int s = 0; s < 2; ++s) {
            int wchunk = wave * 2 + s;
            int id = wchunk * 64 + lane;
            int row = id >> 2, c4 = id & 3;
            __builtin_amdgcn_global_load_lds(
                (const __attribute__((address_space(1))) void*)
                    &A[(size_t)(bm0 + row) * lda + k0 + c4 * 8],
                (__attribute__((address_space(3))) void*)(lA3 + wchunk * 1024),
                16, 0, 0);
            __builtin_amdgcn_global_load_lds(
                (const __attribute__((address_space(1))) void*)
                    &Bt[(size_t)(bn0 + row) * ldb + k0 + c4 * 8],
                (__attribute__((address_space(3))) void*)(lB3 + wchunk * 1024),
                16, 0, 0);
        }
        __syncthreads();
        bf16x8 af[4], bfr[4];
#pragma unroll
        for (int f = 0; f < 4; ++f) {
            af[f]  = *(const bf16x8*)&lA[(wm + f * 16 + ar) * 32 + kc * 8];
            bfr[f] = *(const bf16x8*)&lB[(wn + f * 16 + ar) * 32 + kc * 8];
        }
#pragma unroll
        for (int fm = 0; fm < 4; ++fm)
#pragma unroll
            for (int fn = 0; fn < 4; ++fn)
                acc[fm][fn] = __builtin_amdgcn_mfma_f32_16x16x32_bf16(
                    af[fm], bfr[fn], acc[fm][fn], 0, 0, 0);
    }

    const int rj = (lane >> 4) * 4;
    const int cj = lane & 15;

#pragma unroll
    for (int fm = 0; fm < 4; ++fm) {
#pragma unroll
        for (int fn = 0; fn < 4; ++fn) {
            int r0 = bm0 + wm + fm * 16 + rj;
            int cc = bn0 + wn + fn * 16 + cj;
            if constexpr (MODE == 3) {
                bf16_t* out = (bf16_t*)out_;
                bf16x4 v;
#pragma unroll
                for (int j = 0; j < 4; ++j) v[j] = (bf16_t)acc[fm][fn][j];
                *(bf16x4*)&out[(size_t)cc * sOut + r0] = v;
            } else {  // MODE 4
                float bb = bias[cc];
                if (cc < 512) {
                    bf16_t* o = (bf16_t*)out_;
#pragma unroll
                    for (int j = 0; j < 4; ++j)
                        o[(size_t)(r0 + j) * 512 + cc] = (bf16_t)(acc[fm][fn][j] + bb);
                } else {
                    bf16_t* o = (bf16_t*)out_ + (size_t)B_ * LC_ * C_;
                    int b = r0 >> 9, l0 = r0 & 511;
                    bf16x4 v;
#pragma unroll
                    for (int j = 0; j < 4; ++j) v[j] = (bf16_t)(acc[fm][fn][j] + bb);
                    *(bf16x4*)&o[((size_t)b * C_ + (cc - 512)) * LC_ + l0] = v;
                }
            }
        }
    }
}

// ---------- fused x-transpose + Q-proj + flash attention ----------
// Block: 64 q-rows, 8 waves = 2(M:32q) x 4(N:128cols). grid=512, z=bid&7 XCD pin.
// lQP (64KB, swizzled) holds A-operand: x^T -> Q -> P. Fragments are REGISTER
// double-buffered (af0/bf0 vs af1/bf1): MFMA(t) consumes pre-read regs while
// the LDS pipe reads frags(t+1) -> matrix and LDS pipes overlap.
// lS = 3 x 32KB rotating stream tiles staged 2 ahead; in-loop s_waitcnt vmcnt(4).
__global__ __launch_bounds__(512, 2) void k_flash(
    const bf16_t* __restrict__ Wq_t, const float* __restrict__ bq,
    const bf16_t* __restrict__ Kb, const bf16_t* __restrict__ Vt,
    const float* __restrict__ x, float* __restrict__ out) {
    __shared__ bf16_t lQP[64 * 512];    // 64 KB
    __shared__ bf16_t lS[3][16384];     // 96 KB  (160 KiB total)
    float (*redA)[64] = (float(*)[64])&lQP[0];      // alias: row 0 (dead Q)
    float (*redB)[64] = (float(*)[64])&lQP[512];    // alias: row 1

    const int bid = blockIdx.x;
    const int z = bid & 7;
    const int q0 = (bid >> 3) * 64;
    const int tid = threadIdx.x;
    const int lane = tid & 63;
    const int wave = tid >> 6;
    const int wm2 = wave >> 2;   // 0..1 : 32-q-row group
    const int wn4 = wave & 3;    // 0..3 : 128-col group
    const int h = lane >> 4;     // 0..3
    const int r15 = lane & 15;

    const bf16_t* Kz = Kb + (size_t)z * LC_ * C_;
    const bf16_t* Vz = Vt + (size_t)z * C_ * LC_;
    const float*  xz = x + (size_t)z * C_ * HW_;

    auto lS3 = (__attribute__((address_space(3))) char*)&lS[0][0];

    // stage one [512 rows][32 k] tile (32 KB) into buffer b; source pre-swizzled
    auto STAGE = [&](int b, const bf16_t* __restrict__ src, int t) {
#pragma unroll
        for (int s = 0; s < 4; ++s) {
            int id = s * 512 + tid;
            int row = id >> 2, c4 = id & 3;
            int c4s = c4 ^ (row & 3);
            __builtin_amdgcn_global_load_lds(
                (const __attribute__((address_space(1))) void*)
                    &src[(size_t)row * 512 + t * 32 + c4s * 8],
                (__attribute__((address_space(3))) void*)
                    (lS3 + b * 32768 + s * 8192 + wave * 1024),
                16, 0, 0);
        }
    };

    f32x4 acc[2][8];
    bf16x8 af0[2], bf0[8], af1[2], bf1[8];   // two named frag sets (static toggle)

    auto READF = [&](bf16x8 (&af)[2], bf16x8 (&bfr)[8], int t, int buf) {
        int c16 = t * 4 + h;
#pragma unroll
        for (int m = 0; m < 2; ++m) {
            int row = wm2 * 32 + m * 16 + r15;
            int sc = (c16 & 56) | ((c16 ^ row) & 7);
            af[m] = *(const bf16x8*)&lQP[row * 512 + sc * 8];
        }
        const bf16_t* lb = &lS[buf][0];
#pragma unroll
        for (int n = 0; n < 8; ++n) {
            int row = wn4 * 128 + n * 16 + r15;
            bfr[n] = *(const bf16x8*)&lb[row * 32 + (h ^ (row & 3)) * 8];
        }
    };
    auto MF = [&](bf16x8 (&af)[2], bf16x8 (&bfr)[8]) {
        __builtin_amdgcn_s_setprio(1);
#pragma unroll
        for (int m = 0; m < 2; ++m)
#pragma unroll
            for (int n = 0; n < 8; ++n)
                acc[m][n] = __builtin_amdgcn_mfma_f32_16x16x32_bf16(
                    af[m], bfr[n], acc[m][n], 0, 0, 0);
        __builtin_amdgcn_s_setprio(0);
    };
    auto BAR = [&]() {
        __builtin_amdgcn_sched_barrier(0);
        __builtin_amdgcn_s_barrier();
        __builtin_amdgcn_sched_barrier(0);
    };

    // one 16-step GEMM phase; tile j in buffer (j+off)%3.
    // entry (after __syncthreads): tiles 0,1 staged & LANDED, lQP stable.
    auto PHASE = [&](const bf16_t* __restrict__ src, int off) {
        READF(af0, bf0, 0, off % 3);
#pragma unroll
        for (int tt = 0; tt < 7; ++tt) {
            int t = 2 * tt;
            STAGE((t + 2 + off) % 3, src, t + 2);
            MF(af0, bf0);
            asm volatile("s_waitcnt vmcnt(4)" ::: "memory");
            READF(af1, bf1, t + 1, (t + 1 + off) % 3);
            BAR();
            STAGE((t + 3 + off) % 3, src, t + 3);
            MF(af1, bf1);
            asm volatile("s_waitcnt vmcnt(4)" ::: "memory");
            READF(af0, bf0, t + 2, (t + 2 + off) % 3);
            BAR();
        }
        MF(af0, bf0);                         // t = 14
        asm volatile("s_waitcnt vmcnt(0)" ::: "memory");
        READF(af1, bf1, 15, (15 + off) % 3);
        BAR();
        MF(af1, bf1);                         // t = 15
    };

    // ===== prologue: stage Wq tiles 0,1; x^T -> lQP (bf16, swizzled) =====
    STAGE(0, Wq_t, 0); STAGE(1, Wq_t, 1);
#pragma unroll
    for (int i = 0; i < 16; ++i) {
        int c = i * 32 + (tid >> 4);
        int q = (tid & 15) * 4;
        f32x4 v = *(const f32x4*)&xz[(size_t)c * HW_ + q0 + q];
#pragma unroll
        for (int j = 0; j < 4; ++j) {
            int row = q + j;
            int c16 = c >> 3;
            int sc = (c16 & 56) | ((c16 ^ row) & 7);
            lQP[row * 512 + sc * 8 + (c & 7)] = (bf16_t)v[j];
        }
    }
    __syncthreads();

    // ===== phase 1: Q = x^T @ Wq_t =====
#pragma unroll
    for (int m = 0; m < 2; ++m)
#pragma unroll
        for (int n = 0; n < 8; ++n) acc[m][n] = (f32x4)0.f;
    PHASE(Wq_t, 0);

    // ===== boundary 1: Q (+bq) -> lQP; early K stages =====
    __syncthreads();
    STAGE(1, Kz, 0); STAGE(2, Kz, 1);   // phase-2 mapping: tile j -> buf (j+1)%3
    {
        float bqv[8];
#pragma unroll
        for (int n = 0; n < 8; ++n) bqv[n] = bq[wn4 * 128 + n * 16 + r15];
#pragma unroll
        for (int m = 0; m < 2; ++m)
#pragma unroll
            for (int j = 0; j < 4; ++j) {
                int row = wm2 * 32 + m * 16 + h * 4 + j;
#pragma unroll
                for (int n = 0; n < 8; ++n) {
                    int col = wn4 * 128 + n * 16 + r15;
                    int c16 = col >> 3;
                    int sc = (c16 & 56) | ((c16 ^ row) & 7);
                    lQP[row * 512 + sc * 8 + (col & 7)] = (bf16_t)(acc[m][n][j] + bqv[n]);
                }
            }
    }
    __syncthreads();   // drains K0,K1; Q visible

    // ===== phase 2: S = Q @ K^T =====
#pragma unroll
    for (int m = 0; m < 2; ++m)
#pragma unroll
        for (int n = 0; n < 8; ++n) acc[m][n] = (f32x4)0.f;
    PHASE(Kz, 1);

    // ===== boundary 2: softmax, P -> lQP; early V stages =====
    __syncthreads();
    STAGE(2, Vz, 0); STAGE(0, Vz, 1);   // phase-3 mapping: tile j -> buf (j+2)%3
    const float scale = 0.044194173824159216f;  // 512^-0.5
    float M[2][4], inv[2][4];
#pragma unroll
    for (int m = 0; m < 2; ++m)
#pragma unroll
        for (int j = 0; j < 4; ++j) {
            float v = -1e30f;
#pragma unroll
            for (int n = 0; n < 8; ++n) v = fmaxf(v, acc[m][n][j]);
#pragma unroll
            for (int o = 1; o < 16; o <<= 1) v = fmaxf(v, __shfl_xor(v, o));
            if (r15 == 0) redA[wn4][wm2 * 32 + m * 16 + h * 4 + j] = v;
        }
    __syncthreads();
#pragma unroll
    for (int m = 0; m < 2; ++m)
#pragma unroll
        for (int j = 0; j < 4; ++j) {
            int row = wm2 * 32 + m * 16 + h * 4 + j;
            M[m][j] = fmaxf(fmaxf(redA[0][row], redA[1][row]),
                            fmaxf(redA[2][row], redA[3][row]));
        }
#pragma unroll
    for (int m = 0; m < 2; ++m)
#pragma unroll
        for (int j = 0; j < 4; ++j) {
            float s = 0.f;
#pragma unroll
            for (int n = 0; n < 8; ++n) {
                float e = __expf((acc[m][n][j] - M[m][j]) * scale);
                acc[m][n][j] = e;
                s += e;
            }
#pragma unroll
            for (int o = 1; o < 16; o <<= 1) s += __shfl_xor(s, o);
            if (r15 == 0) redB[wn4][wm2 * 32 + m * 16 + h * 4 + j] = s;
        }
    __syncthreads();
#pragma unroll
    for (int m = 0; m < 2; ++m)
#pragma unroll
        for (int j = 0; j < 4; ++j) {
            int row = wm2 * 32 + m * 16 + h * 4 + j;
            inv[m][j] = 1.f / (redB[0][row] + redB[1][row] +
                               redB[2][row] + redB[3][row]);
        }
    __syncthreads();   // red reads done before P overwrites lQP
    // write P (bf16, swizzled) into lQP
#pragma unroll
    for (int m = 0; m < 2; ++m)
#pragma unroll
        for (int j = 0; j < 4; ++j) {
            int row = wm2 * 32 + m * 16 + h * 4 + j;
#pragma unroll
            for (int n = 0; n < 8; ++n) {
                int col = wn4 * 128 + n * 16 + r15;
                int c16 = col >> 3;
                int sc = (c16 & 56) | ((c16 ^ row) & 7);
                lQP[row * 512 + sc * 8 + (col & 7)] = (bf16_t)(acc[m][n][j] * inv[m][j]);
            }
        }
    __syncthreads();   // drains V0,V1; P visible

    // ===== phase 3: O = P @ V =====
#pragma unroll
    for (int m = 0; m < 2; ++m)
#pragma unroll
        for (int n = 0; n < 8; ++n) acc[m][n] = (f32x4)0.f;
    PHASE(Vz, 2);

    // ===== epilogue: out[c][hw] = O + x[c][hw] =====
    float* oz = out + (size_t)z * C_ * HW_;
#pragma unroll
    for (int m = 0; m < 2; ++m)
#pragma unroll
        for (int n = 0; n < 8; ++n) {
            int r0 = q0 + wm2 * 32 + m * 16 + h * 4;
            int cc = wn4 * 128 + n * 16 + r15;
            f32x4 xv = *(const f32x4*)&xz[(size_t)cc * HW_ + r0];
            f32x4 o;
#pragma unroll
            for (int j = 0; j < 4; ++j) o[j] = acc[m][n][j] + xv[j];
            *(f32x4*)&oz[(size_t)cc * HW_ + r0] = o;
        }
}

extern "C" void kernel_launch(void* const* d_in, const int* in_sizes, int n_in,
                              void* d_out, int out_size, void* d_ws, size_t ws_size,
                              hipStream_t stream) {
    (void)in_sizes; (void)n_in; (void)out_size; (void)ws_size;
    const float* x   = (const float*)d_in[0];
    const float* ctx = (const float*)d_in[1];
    const float* Wq  = (const float*)d_in[2];
    const float* bq  = (const float*)d_in[3];
    const float* Wk  = (const float*)d_in[4];
    const float* bk  = (const float*)d_in[5];
    const float* Wv  = (const float*)d_in[6];
    const float* bv  = (const float*)d_in[7];
    const float* Wo  = (const float*)d_in[8];
    const float* bo  = (const float*)d_in[9];
    float* out = (float*)d_out;

    char* ws = (char*)d_ws;
    size_t off = 0;
    auto alloc = [&](size_t bytes) {
        char* p = ws + off;
        off += (bytes + 255) & ~(size_t)255;
        return p;
    };
    bf16_t* Wq_t  = (bf16_t*)alloc((size_t)C_ * C_ * 2);
    bf16_t* Wk_t  = (bf16_t*)alloc((size_t)C_ * CTX_ * 2);   // adjacent ...
    bf16_t* Wvo_t = (bf16_t*)alloc((size_t)C_ * CTX_ * 2);   // ... to Wk_t (N=1024 concat)
    bf16_t* Wv_b  = (bf16_t*)alloc((size_t)CTX_ * C_ * 2);
    bf16_t* Wo_t  = (bf16_t*)alloc((size_t)C_ * C_ * 2);
    float*  bkvo  = (float*)alloc((size_t)1024 * 4);
    bf16_t* ctxb  = (bf16_t*)alloc((size_t)B_ * LC_ * CTX_ * 2);
    bf16_t* Kb    = (bf16_t*)alloc((size_t)B_ * LC_ * C_ * 2);  // adjacent ...
    bf16_t* Vt    = (bf16_t*)alloc((size_t)B_ * C_ * LC_ * 2);  // ... to Kb (MODE 4)

    // weight prep
    k_transpose_w<<<dim3(C_ / 32, C_ / 32), dim3(32, 8), 0, stream>>>(Wq, Wq_t, C_, C_);
    k_transpose_w<<<dim3(CTX_ / 32, C_ / 32), dim3(32, 8), 0, stream>>>(Wk, Wk_t, CTX_, C_);
    k_transpose_w<<<dim3(C_ / 32, C_ / 32), dim3(32, 8), 0, stream>>>(Wo, Wo_t, C_, C_);
    k_f32_to_bf16<<<(CTX_ * C_ / 4 + 255) / 256, 256, 0, stream>>>(Wv, Wv_b, CTX_ * C_);
    k_bias<<<130, 256, 0, stream>>>(bk, bv, Wo_t, bo, bkvo);
    k_f32_to_bf16<<<(B_ * LC_ * CTX_ / 4 + 255) / 256, 256, 0, stream>>>(
        ctx, ctxb, B_ * LC_ * CTX_);

    // Wvo_t = (Wv @ Wo)^T
    k_gemm<3><<<dim3(4, 6, 1), 256, 0, stream>>>(
        Wv_b, C_, 0, Wo_t, C_, 0, nullptr, Wvo_t, CTX_, C_, C_, 1.f);
    // merged: [K | V'] = ctx @ [Wk | Wvo] + bkvo  (one 256-block launch)
    k_gemm<4><<<dim3(8, 32, 1), 256, 0, stream>>>(
        ctxb, CTX_, 0, Wk_t, CTX_, 0, bkvo, Kb, 0, 1024, CTX_, 1.f);
    // fused x-transpose + Q-projection + attention + residual
    k_flash<<<512, 512, 0, stream>>>(Wq_t, bq, Kb, Vt, x, out);
}